// Round 7
// baseline (942.837 us; speedup 1.0000x reference)
//
#include <hip/hip_runtime.h>
#include <cstdint>
#include <cstddef>

#define NN 262144
#define EE 1048576
#define BB 512
#define SEG 512

// ---------------- Threefry-2x32 (exact JAX replica) ----------------
__device__ __forceinline__ unsigned rotl32(unsigned x, int r) {
    return (x << r) | (x >> (32 - r));
}

__device__ __forceinline__ void tf2x32(unsigned k0, unsigned k1, unsigned x0, unsigned x1,
                                       unsigned& o0, unsigned& o1) {
    unsigned ks[3] = {k0, k1, k0 ^ k1 ^ 0x1BD11BDAu};
    x0 += ks[0]; x1 += ks[1];
    const int R0[4] = {13, 15, 26, 6};
    const int R1[4] = {17, 29, 16, 24};
#pragma unroll
    for (int i = 0; i < 5; ++i) {
        const int* R = (i & 1) ? R1 : R0;
#pragma unroll
        for (int j = 0; j < 4; ++j) {
            x0 += x1;
            x1 = rotl32(x1, R[j]);
            x1 ^= x0;
        }
        x0 += ks[(i + 1) % 3];
        x1 += ks[(i + 2) % 3] + (unsigned)(i + 1);
    }
    o0 = x0; o1 = x1;
}

__device__ __forceinline__ float unif_loc(unsigned idx) {
    unsigned j = idx & (NN / 2 - 1);
    unsigned half = idx >> 17;
    unsigned o0, o1;
    tf2x32(0u, 42u, j, j + (unsigned)(NN / 2), o0, o1);
    unsigned bits = half ? o1 : o0;
    float f = __uint_as_float((bits >> 9) | 0x3F800000u) - 1.0f;
    const float minv = 1e-6f;
    const float maxv = 1.0f - 1e-6f;
    const float span = maxv - minv;
    return fmaxf(minv, __fadd_rn(__fmul_rn(f, span), minv));
}

// ---------------- CSR build ----------------
__global__ void csr_count(const int* __restrict__ dst, int* __restrict__ counts, int E) {
    int i = blockIdx.x * 256 + threadIdx.x;
    if (i < E) atomicAdd(&counts[dst[i]], 1);
}

__global__ void scan512(const int* __restrict__ in, int* __restrict__ outExcl, int* __restrict__ bsum) {
    __shared__ int s[512];
    int b = blockIdx.x, tid = threadIdx.x;
    int v = in[(size_t)b * 512 + tid];
    s[tid] = v;
    __syncthreads();
    for (int d = 1; d < 512; d <<= 1) {
        int add = (tid >= d) ? s[tid - d] : 0;
        __syncthreads();
        s[tid] += add;
        __syncthreads();
    }
    outExcl[(size_t)b * 512 + tid] = s[tid] - v;
    if (tid == 511) bsum[b] = s[511];
}

__global__ void scan_fix(int* __restrict__ offs, const int* __restrict__ bbase,
                         int* __restrict__ cursor, int N, int E) {
    int gid = blockIdx.x * 512 + threadIdx.x;
    int v = offs[gid] + bbase[blockIdx.x];
    offs[gid] = v;
    cursor[gid] = v;
    if (gid == 0) offs[N] = E;
}

__global__ void csr_fill(const int* __restrict__ dst, const int* __restrict__ src,
                         const float4* __restrict__ ea, int* __restrict__ cursor,
                         int* __restrict__ ssrc, float4* __restrict__ sea, int E) {
    int i = blockIdx.x * 256 + threadIdx.x;
    if (i < E) {
        int p = atomicAdd(&cursor[dst[i]], 1);
        ssrc[p] = src[i];
        sea[p] = ea[i];
    }
}

// ---------------- Layer 0: aggregate (dim 8) ----------------
__global__ void agg_l0(const float* __restrict__ x, const int* __restrict__ ssrc,
                       const float4* __restrict__ sea, const int* __restrict__ offs,
                       const float* __restrict__ We0, const float* __restrict__ be0,
                       float* __restrict__ out) {
    __shared__ float Ws[32];
    __shared__ float bs[8];
    int tid = threadIdx.x;
    if (tid < 32) Ws[tid] = We0[tid];
    if (tid < 8) bs[tid] = be0[tid];
    __syncthreads();
    int n = blockIdx.x * 256 + tid;
    float a[8] = {0.f, 0.f, 0.f, 0.f, 0.f, 0.f, 0.f, 0.f};
    int pb = offs[n], pe = offs[n + 1];
    for (int p = pb; p < pe; ++p) {
        int s = ssrc[p];
        float4 ev = sea[p];
        float4 xa = *(const float4*)(x + (size_t)s * 8);
        float4 xb = *(const float4*)(x + (size_t)s * 8 + 4);
        float xs[8] = {xa.x, xa.y, xa.z, xa.w, xb.x, xb.y, xb.z, xb.w};
#pragma unroll
        for (int j2 = 0; j2 < 8; ++j2) {
            float m = xs[j2] + bs[j2] + ev.x * Ws[j2] + ev.y * Ws[8 + j2] +
                      ev.z * Ws[16 + j2] + ev.w * Ws[24 + j2];
            a[j2] += fmaxf(m, 0.f);
        }
    }
    float4 o0 = {a[0], a[1], a[2], a[3]};
    float4 o1 = {a[4], a[5], a[6], a[7]};
    *(float4*)(out + (size_t)n * 8) = o0;
    *(float4*)(out + (size_t)n * 8 + 4) = o1;
}

// ---------------- Layer 0 update ----------------
__global__ __launch_bounds__(256) void update_l0(const float* __restrict__ x,
                                                 const float* __restrict__ agg0,
                                                 const float* __restrict__ W0,
                                                 const float* __restrict__ b0,
                                                 float* __restrict__ h1) {
    __shared__ float Ws[8 * 128];
    __shared__ float bs[128];
    int tid = threadIdx.x;
#pragma unroll
    for (int i = tid; i < 1024; i += 256) Ws[i] = W0[i];
    if (tid < 128) bs[tid] = b0[tid];
    __syncthreads();
    int sub = tid >> 7;
    int c = tid & 127;
    float bias = bs[c];
    float wcol[8];
#pragma unroll
    for (int k = 0; k < 8; ++k) wcol[k] = Ws[k * 128 + c];
    int base = blockIdx.x * 128;
    for (int it = 0; it < 64; ++it) {
        int node = base + it * 2 + sub;
        const float* xp = x + (size_t)node * 8;
        const float* ap = agg0 + (size_t)node * 8;
        float4 xa = *(const float4*)xp;
        float4 xb = *(const float4*)(xp + 4);
        float4 aa = *(const float4*)ap;
        float4 ab = *(const float4*)(ap + 4);
        float t[8] = {xa.x + aa.x, xa.y + aa.y, xa.z + aa.z, xa.w + aa.w,
                      xb.x + ab.x, xb.y + ab.y, xb.z + ab.z, xb.w + ab.w};
        float acc = bias;
#pragma unroll
        for (int k = 0; k < 8; ++k) acc = fmaf(t[k], wcol[k], acc);
        h1[(size_t)node * 128 + c] = fmaxf(acc, 0.f);
    }
}

// ---------------- Layers 1,2: fused msg+aggregate+SELF ----------------
// 8 consecutive nodes per wave; scalar boundary chain + flush (round 2).
// NEW: out[node] = h2[node] + sum(relu(msg)) — the self term of the GINE
// update is folded in here so the GEMM becomes single-input. Self rows are
// preloaded into a register shift-chain (statically indexed, mirrors the
// boundary chain).
__global__ __launch_bounds__(256) void agg_l(const float2* __restrict__ h2,
                                             const int* __restrict__ ssrc,
                                             const float4* __restrict__ sea,
                                             const int* __restrict__ offs,
                                             const float* __restrict__ We,
                                             const float* __restrict__ be,
                                             float2* __restrict__ out) {
    int tid = threadIdx.x;
    int lane = tid & 63;
    int n0 = blockIdx.x * 32 + (tid >> 6) * 8;
    n0 = __builtin_amdgcn_readfirstlane(n0);
    const float2* We2 = (const float2*)We;
    float2 w0 = We2[lane], w1 = We2[64 + lane], w2 = We2[128 + lane], w3 = We2[192 + lane];
    float2 bv = ((const float2*)be)[lane];

    int b0  = __builtin_amdgcn_readfirstlane(offs[n0 + 0]);
    int nb0 = __builtin_amdgcn_readfirstlane(offs[n0 + 1]);
    int nb1 = __builtin_amdgcn_readfirstlane(offs[n0 + 2]);
    int nb2 = __builtin_amdgcn_readfirstlane(offs[n0 + 3]);
    int nb3 = __builtin_amdgcn_readfirstlane(offs[n0 + 4]);
    int nb4 = __builtin_amdgcn_readfirstlane(offs[n0 + 5]);
    int nb5 = __builtin_amdgcn_readfirstlane(offs[n0 + 6]);
    int nb6 = __builtin_amdgcn_readfirstlane(offs[n0 + 7]);
    int nb7 = __builtin_amdgcn_readfirstlane(offs[n0 + 8]);
    int pend = nb7;

    // self rows for the 8 nodes (register shift-chain)
    float2 sf1 = h2[(size_t)(n0 + 1) * 64 + lane];
    float2 sf2 = h2[(size_t)(n0 + 2) * 64 + lane];
    float2 sf3 = h2[(size_t)(n0 + 3) * 64 + lane];
    float2 sf4 = h2[(size_t)(n0 + 4) * 64 + lane];
    float2 sf5 = h2[(size_t)(n0 + 5) * 64 + lane];
    float2 sf6 = h2[(size_t)(n0 + 6) * 64 + lane];
    float2 sf7 = h2[(size_t)(n0 + 7) * 64 + lane];
    float2 acc = h2[(size_t)(n0 + 0) * 64 + lane];   // self of first node

    float2* optr = out + (size_t)n0 * 64 + lane;

#define FLUSH(pp)                                          \
    while ((pp) == nb0) {                                  \
        *optr = acc;                                       \
        optr += 64;                                        \
        nb0 = nb1; nb1 = nb2; nb2 = nb3; nb3 = nb4;        \
        nb4 = nb5; nb5 = nb6; nb6 = nb7; nb7 = 0x7FFFFFFF; \
        acc = sf1;                                         \
        sf1 = sf2; sf2 = sf3; sf3 = sf4; sf4 = sf5;        \
        sf5 = sf6; sf6 = sf7;                              \
    }

#define ACC(hv, ev)                                                                     \
    {                                                                                   \
        float mx = hv.x + bv.x + ev.x * w0.x + ev.y * w1.x + ev.z * w2.x + ev.w * w3.x; \
        float my = hv.y + bv.y + ev.x * w0.y + ev.y * w1.y + ev.z * w2.y + ev.w * w3.y; \
        acc.x += fmaxf(mx, 0.f);                                                        \
        acc.y += fmaxf(my, 0.f);                                                        \
    }

    int p = b0;
    for (; p + 8 <= pend; p += 8) {
        int s_[8];
#pragma unroll
        for (int j = 0; j < 8; ++j) s_[j] = ssrc[p + j];
        float4 e_[8];
#pragma unroll
        for (int j = 0; j < 8; ++j) e_[j] = sea[p + j];
        float2 h_[8];
#pragma unroll
        for (int j = 0; j < 8; ++j) h_[j] = h2[(size_t)s_[j] * 64 + lane];
#pragma unroll
        for (int j = 0; j < 8; ++j) {
            FLUSH(p + j)
            ACC(h_[j], e_[j])
        }
    }
    for (; p < pend; ++p) {
        FLUSH(p)
        int s0 = ssrc[p];
        float4 e0 = sea[p];
        float2 ha = h2[(size_t)s0 * 64 + lane];
        ACC(ha, e0)
    }
    FLUSH(pend)
#undef ACC
#undef FLUSH
}

// ====== split-bf16 MFMA GEMM, single input, 64 rows/wave ======
// C = relu(P @ W + b). agg_l already folded the self term, so only one
// input matrix. 64 output rows per wave (acc[4][8]) doubles per-wave
// memory-level parallelism vs 32 rows. In-place P==out is safe: the wave
// reads only its own 64 rows, all loads precede its stores (acc deps).
// NOTE: P deliberately NOT __restrict__ (aliases out when in-place).

typedef __attribute__((ext_vector_type(8))) short bf16x8;
typedef __attribute__((ext_vector_type(4))) float f32x4;

__device__ __forceinline__ ushort bf16r(float x) {   // fp32 -> bf16 RNE bits
    unsigned u = __float_as_uint(x);
    return (ushort)((u + 0x7FFFu + ((u >> 16) & 1u)) >> 16);
}
__device__ __forceinline__ float bf2f(ushort h) {
    return __uint_as_float(((unsigned)h) << 16);
}

// Pack W [128x128 row-major, k-major] into MFMA B-fragments, hi+lo.
// Fragment slot j of lane l (kc,n tile) = W[kc*32 + (l>>4)*8 + j][n*16 + (l&15)].
// dst layout per matrix: hi[2048 uint4] then lo[2048 uint4] (32KB each).
__global__ void pack3(const float* __restrict__ W1, const float* __restrict__ W2,
                      const float* __restrict__ LA, uint4* __restrict__ dst) {
    const float* W = (blockIdx.x == 0) ? W1 : (blockIdx.x == 1) ? W2 : LA;
    uint4* ph = dst + (size_t)blockIdx.x * 4096;
    uint4* pl = ph + 2048;
    int t = threadIdx.x;
    int l = t & 63, q = t >> 6;
    int lo = l & 15, kg = l >> 4;
    for (int i = 0; i < 8; ++i) {
        int combo = q * 8 + i;          // 0..31 = (kc, n)
        int kc = combo >> 3, n = combo & 7;
        ushort h8[8], l8[8];
#pragma unroll
        for (int j = 0; j < 8; ++j) {
            float wv = W[(size_t)(kc * 32 + kg * 8 + j) * 128 + n * 16 + lo];
            ushort hh = bf16r(wv);
            h8[j] = hh;
            l8[j] = bf16r(wv - bf2f(hh));
        }
        int idx = (kc * 8 + n) * 64 + l;
        ph[idx] = *(const uint4*)h8;
        pl[idx] = *(const uint4*)l8;
    }
}

__device__ __forceinline__ void conv_frag(const float4& r0, const float4& r1,
                                          bf16x8& ah, bf16x8& al) {
    float av[8] = {r0.x, r0.y, r0.z, r0.w, r1.x, r1.y, r1.z, r1.w};
#pragma unroll
    for (int j = 0; j < 8; ++j) {
        ushort hh = bf16r(av[j]);
        ah[j] = (short)hh;
        al[j] = (short)bf16r(av[j] - bf2f(hh));
    }
}

__global__ __launch_bounds__(256, 2) void gemm_mfma(const float* P,
                                                    const uint4* __restrict__ Wh,
                                                    const uint4* __restrict__ Wl,
                                                    const float* __restrict__ bias,
                                                    float* out) {
    int tid = threadIdx.x;
    int w = tid >> 6, l = tid & 63;
    int r0 = blockIdx.x * 256 + w * 64;
    int lo = l & 15, kg = l >> 4;
    const bf16x8* Bh = (const bf16x8*)Wh;
    const bf16x8* Bl = (const bf16x8*)Wl;
    f32x4 acc[4][8];
#pragma unroll
    for (int m = 0; m < 4; ++m)
#pragma unroll
        for (int n = 0; n < 8; ++n) acc[m][n] = (f32x4){0.f, 0.f, 0.f, 0.f};

    for (int kc = 0; kc < 4; ++kc) {
        // A: 4 m-fragments (8 independent float4 loads issued back-to-back)
        float4 pa[8];
#pragma unroll
        for (int m = 0; m < 4; ++m) {
            const float* ap = P + (size_t)(r0 + m * 16 + lo) * 128 + kc * 32 + kg * 8;
            pa[2 * m]     = *(const float4*)ap;
            pa[2 * m + 1] = *(const float4*)(ap + 4);
        }
        bf16x8 ah[4], al[4];
#pragma unroll
        for (int m = 0; m < 4; ++m)
            conv_frag(pa[2 * m], pa[2 * m + 1], ah[m], al[m]);
#pragma unroll
        for (int h2i = 0; h2i < 2; ++h2i) {
            bf16x8 bh[4], bl[4];
#pragma unroll
            for (int nn = 0; nn < 4; ++nn) {
                int idx = (kc * 8 + h2i * 4 + nn) * 64 + l;
                bh[nn] = Bh[idx];
                bl[nn] = Bl[idx];
            }
#pragma unroll
            for (int nn = 0; nn < 4; ++nn) {
                int n = h2i * 4 + nn;
#pragma unroll
                for (int m = 0; m < 4; ++m) {
                    acc[m][n] = __builtin_amdgcn_mfma_f32_16x16x32_bf16(ah[m], bh[nn], acc[m][n], 0, 0, 0);
                    acc[m][n] = __builtin_amdgcn_mfma_f32_16x16x32_bf16(al[m], bh[nn], acc[m][n], 0, 0, 0);
                    acc[m][n] = __builtin_amdgcn_mfma_f32_16x16x32_bf16(ah[m], bl[nn], acc[m][n], 0, 0, 0);
                }
            }
        }
    }
    // D layout (m89-verified): col = l&15, row = (l>>4)*4 + v
    float bv[8];
#pragma unroll
    for (int n = 0; n < 8; ++n) bv[n] = bias[n * 16 + lo];
#pragma unroll
    for (int m = 0; m < 4; ++m)
#pragma unroll
        for (int n = 0; n < 8; ++n)
#pragma unroll
            for (int v = 0; v < 4; ++v) {
                size_t g = (size_t)(r0 + m * 16 + kg * 4 + v) * 128 + n * 16 + lo;
                out[g] = fmaxf(acc[m][n][v] + bv[n], 0.f);
            }
}

// fused actor head: L = relu(emb@laW1+lab1)@laW2 + lab2 (same 64-row tile)
__global__ __launch_bounds__(256, 2) void gemm_logit_mfma(const float* __restrict__ P,
                                                          const uint4* __restrict__ Wh,
                                                          const uint4* __restrict__ Wl,
                                                          const float* __restrict__ bias,
                                                          const float* __restrict__ w2,
                                                          const float* __restrict__ b2,
                                                          float* __restrict__ L) {
    int tid = threadIdx.x;
    int w = tid >> 6, l = tid & 63;
    int r0 = blockIdx.x * 256 + w * 64;
    int lo = l & 15, kg = l >> 4;
    const bf16x8* Bh = (const bf16x8*)Wh;
    const bf16x8* Bl = (const bf16x8*)Wl;
    f32x4 acc[4][8];
#pragma unroll
    for (int m = 0; m < 4; ++m)
#pragma unroll
        for (int n = 0; n < 8; ++n) acc[m][n] = (f32x4){0.f, 0.f, 0.f, 0.f};

    for (int kc = 0; kc < 4; ++kc) {
        float4 pa[8];
#pragma unroll
        for (int m = 0; m < 4; ++m) {
            const float* ap = P + (size_t)(r0 + m * 16 + lo) * 128 + kc * 32 + kg * 8;
            pa[2 * m]     = *(const float4*)ap;
            pa[2 * m + 1] = *(const float4*)(ap + 4);
        }
        bf16x8 ah[4], al[4];
#pragma unroll
        for (int m = 0; m < 4; ++m)
            conv_frag(pa[2 * m], pa[2 * m + 1], ah[m], al[m]);
#pragma unroll
        for (int h2i = 0; h2i < 2; ++h2i) {
            bf16x8 bh[4], bl[4];
#pragma unroll
            for (int nn = 0; nn < 4; ++nn) {
                int idx = (kc * 8 + h2i * 4 + nn) * 64 + l;
                bh[nn] = Bh[idx];
                bl[nn] = Bl[idx];
            }
#pragma unroll
            for (int nn = 0; nn < 4; ++nn) {
                int n = h2i * 4 + nn;
#pragma unroll
                for (int m = 0; m < 4; ++m) {
                    acc[m][n] = __builtin_amdgcn_mfma_f32_16x16x32_bf16(ah[m], bh[nn], acc[m][n], 0, 0, 0);
                    acc[m][n] = __builtin_amdgcn_mfma_f32_16x16x32_bf16(al[m], bh[nn], acc[m][n], 0, 0, 0);
                    acc[m][n] = __builtin_amdgcn_mfma_f32_16x16x32_bf16(ah[m], bl[nn], acc[m][n], 0, 0, 0);
                }
            }
        }
    }
    float bv[8], w2v[8];
#pragma unroll
    for (int n = 0; n < 8; ++n) {
        bv[n] = bias[n * 16 + lo];
        w2v[n] = w2[n * 16 + lo];
    }
    float b2v = b2[0];
#pragma unroll
    for (int m = 0; m < 4; ++m)
#pragma unroll
        for (int v = 0; v < 4; ++v) {
            float s = 0.f;
#pragma unroll
            for (int n = 0; n < 8; ++n)
                s += fmaxf(acc[m][n][v] + bv[n], 0.f) * w2v[n];
            s += __shfl_xor(s, 8);
            s += __shfl_xor(s, 4);
            s += __shfl_xor(s, 2);
            s += __shfl_xor(s, 1);
            if (lo == 0) L[r0 + m * 16 + kg * 4 + v] = s + b2v;
        }
}

// ---------------- per-graph softmax + Gumbel-max sampling ----------------
__global__ void sample_k(const float* __restrict__ L, float* __restrict__ ob,
                         int* __restrict__ locInt) {
    int g = blockIdx.x, tid = threadIdx.x;
    __shared__ float sh[512];
    __shared__ float rb[256];
    __shared__ int ib[256];
    float l0 = L[g * 512 + tid];
    float l1 = L[g * 512 + 256 + tid];
    rb[tid] = fmaxf(l0, l1);
    __syncthreads();
    for (int s2 = 128; s2 > 0; s2 >>= 1) {
        if (tid < s2) rb[tid] = fmaxf(rb[tid], rb[tid + s2]);
        __syncthreads();
    }
    float mx = rb[0];
    __syncthreads();
    float s0 = l0 - mx, s1 = l1 - mx;
    sh[tid] = s0; sh[256 + tid] = s1;
    float e0 = expf(s0), e1 = expf(s1);
    rb[tid] = e0 + e1;
    __syncthreads();
    for (int s2 = 128; s2 > 0; s2 >>= 1) {
        if (tid < s2) rb[tid] += rb[tid + s2];
        __syncthreads();
    }
    float denom = rb[0];
    __syncthreads();
    rb[tid] = e0 * s0 + e1 * s1;
    __syncthreads();
    for (int s2 = 128; s2 > 0; s2 >>= 1) {
        if (tid < s2) rb[tid] += rb[tid + s2];
        __syncthreads();
    }
    float sum2 = rb[0];
    __syncthreads();
    unsigned i0 = (unsigned)(g * 512 + tid);
    unsigned i1 = i0 + 256u;
    float p0 = l0 - logf(-logf(unif_loc(i0)));
    float p1 = l1 - logf(-logf(unif_loc(i1)));
    rb[tid] = fmaxf(p0, p1);
    __syncthreads();
    for (int s2 = 128; s2 > 0; s2 >>= 1) {
        if (tid < s2) rb[tid] = fmaxf(rb[tid], rb[tid + s2]);
        __syncthreads();
    }
    float pmax = rb[0];
    __syncthreads();
    int c0 = (p0 >= pmax) ? tid : 0x7FFFFFFF;
    int c1 = (p1 >= pmax) ? (tid + 256) : 0x7FFFFFFF;
    ib[tid] = min(c0, c1);
    __syncthreads();
    for (int s2 = 128; s2 > 0; s2 >>= 1) {
        if (tid < s2) ib[tid] = min(ib[tid], ib[tid + s2]);
        __syncthreads();
    }
    if (tid == 0) {
        int li = ib[0];
        float logD = logf(denom);
        ob[g] = (float)(g * 512 + li);
        ob[1024 + g] = sh[li] - logD;
        ob[2048 + g] = logD - sum2 / denom;
        locInt[g] = g * 512 + li;
    }
}

// ---------------- pooled = segment_sum(emb) ----------------
__global__ void pool_k(const float* __restrict__ emb, float* __restrict__ pooled) {
    int g = blockIdx.x, tid = threadIdx.x;
    int c = tid & 127, rg = tid >> 7;
    __shared__ float sh[512];
    float s0 = 0.f, s1 = 0.f, s2 = 0.f, s3 = 0.f;
    const float* base = emb + ((size_t)g * 512 + (size_t)rg * 128) * 128 + c;
    for (int n = 0; n < 128; n += 4) {
        s0 += base[(size_t)(n + 0) * 128];
        s1 += base[(size_t)(n + 1) * 128];
        s2 += base[(size_t)(n + 2) * 128];
        s3 += base[(size_t)(n + 3) * 128];
    }
    sh[tid] = (s0 + s1) + (s2 + s3);
    __syncthreads();
    if (rg == 0) pooled[g * 128 + c] = sh[c] + sh[128 + c] + sh[256 + c] + sh[384 + c];
}

// ---------------- heads ----------------
__global__ void heads_k(const float* __restrict__ emb, const float* __restrict__ pooled,
                        const int* __restrict__ locInt,
                        const float* __restrict__ maW1, const float* __restrict__ mab1,
                        const float* __restrict__ maW2, const float* __restrict__ mab2,
                        const float* __restrict__ lcW1, const float* __restrict__ lcb1,
                        const float* __restrict__ lcW2, const float* __restrict__ lcb2,
                        const float* __restrict__ mcW1, const float* __restrict__ mcb1,
                        const float* __restrict__ mcW2, const float* __restrict__ mcb2,
                        float* __restrict__ ob) {
    int g = blockIdx.x, tid = threadIdx.x;
    __shared__ float sel[128], pl[128];
    __shared__ float red[4][128];
    __shared__ float red1[128];
    __shared__ float mcv_sh;
    sel[tid] = emb[(size_t)locInt[g] * 128 + tid];
    pl[tid] = pooled[g * 128 + tid];
    __syncthreads();
    float h = mab1[tid];
    for (int k = 0; k < 128; ++k) h = fmaf(sel[k], maW1[k * 128 + tid], h);
    h = fmaxf(h, 0.f);
    red[0][tid] = h * maW2[tid * 4 + 0];
    red[1][tid] = h * maW2[tid * 4 + 1];
    red[2][tid] = h * maW2[tid * 4 + 2];
    red[3][tid] = h * maW2[tid * 4 + 3];
    __syncthreads();
    for (int s2 = 64; s2 > 0; s2 >>= 1) {
        if (tid < s2) {
            red[0][tid] += red[0][tid + s2];
            red[1][tid] += red[1][tid + s2];
            red[2][tid] += red[2][tid + s2];
            red[3][tid] += red[3][tid + s2];
        }
        __syncthreads();
    }
    float h2 = mcb1[tid];
    for (int k = 0; k < 128; ++k) h2 = fmaf(sel[k], mcW1[k * 128 + tid], h2);
    h2 = fmaxf(h2, 0.f);
    red1[tid] = h2 * mcW2[tid];
    __syncthreads();
    for (int s2 = 64; s2 > 0; s2 >>= 1) {
        if (tid < s2) red1[tid] += red1[tid + s2];
        __syncthreads();
    }
    if (tid == 0) mcv_sh = red1[0] + mcb2[0];
    __syncthreads();
    float h3 = lcb1[tid];
    for (int k = 0; k < 128; ++k) h3 = fmaf(pl[k], lcW1[k * 128 + tid], h3);
    h3 = fmaxf(h3, 0.f);
    red1[tid] = h3 * lcW2[tid];
    __syncthreads();
    for (int s2 = 64; s2 > 0; s2 >>= 1) {
        if (tid < s2) red1[tid] += red1[tid + s2];
        __syncthreads();
    }
    if (tid == 0) {
        float lcv = red1[0] + lcb2[0];
        float lg[4];
#pragma unroll
        for (int c = 0; c < 4; ++c) lg[c] = red[c][0] + mab2[c];
        unsigned fk0, fk1;
        tf2x32(0u, 42u, 0u, 1u, fk0, fk1);
        float gmb[4];
#pragma unroll
        for (int c = 0; c < 4; ++c) {
            unsigned m = (unsigned)(g * 4 + c);
            unsigned j = m & 1023u;
            unsigned halfb = m >> 10;
            unsigned o0, o1;
            tf2x32(fk0, fk1, j, j + 1024u, o0, o1);
            unsigned bits = halfb ? o1 : o0;
            float f = __uint_as_float((bits >> 9) | 0x3F800000u) - 1.0f;
            const float tiny = 1.17549435e-38f;
            float u = fmaxf(tiny, __fadd_rn(__fmul_rn(f, 1.0f), tiny));
            gmb[c] = -logf(-logf(u));
        }
        int best = 0;
        float bz = gmb[0] + lg[0];
#pragma unroll
        for (int c = 1; c < 4; ++c) {
            float z = gmb[c] + lg[c];
            if (z > bz) { bz = z; best = c; }
        }
        float M = fmaxf(fmaxf(lg[0], lg[1]), fmaxf(lg[2], lg[3]));
        float se = 0.f;
#pragma unroll
        for (int c = 0; c < 4; ++c) se += expf(lg[c] - M);
        float lse = M + logf(se);
        float ent = 0.f;
#pragma unroll
        for (int c = 0; c < 4; ++c) {
            float lp = lg[c] - lse;
            ent -= expf(lp) * lp;
        }
        ob[512 + g] = (float)best;
        ob[1536 + g] = lg[best] - lse;
        ob[2560 + g] = ent;
        ob[3072 + g] = lcv;
        ob[3584 + g] = mcv_sh;
    }
}

// ---------------- launch ----------------
extern "C" void kernel_launch(void* const* d_in, const int* in_sizes, int n_in,
                              void* d_out, int out_size, void* d_ws, size_t ws_size,
                              hipStream_t stream) {
    const float* x   = (const float*)d_in[0];
    const int* ei    = (const int*)d_in[1];
    const float* ea  = (const float*)d_in[2];
    const float* We0 = (const float*)d_in[5];
    const float* be0 = (const float*)d_in[6];
    const float* W0  = (const float*)d_in[7];
    const float* b0  = (const float*)d_in[8];
    const float* We1 = (const float*)d_in[9];
    const float* be1 = (const float*)d_in[10];
    const float* W1  = (const float*)d_in[11];
    const float* b1  = (const float*)d_in[12];
    const float* We2 = (const float*)d_in[13];
    const float* be2 = (const float*)d_in[14];
    const float* W2  = (const float*)d_in[15];
    const float* b2  = (const float*)d_in[16];
    const float* laW1 = (const float*)d_in[17];
    const float* lab1 = (const float*)d_in[18];
    const float* laW2 = (const float*)d_in[19];
    const float* lab2 = (const float*)d_in[20];
    const float* maW1 = (const float*)d_in[21];
    const float* mab1 = (const float*)d_in[22];
    const float* maW2 = (const float*)d_in[23];
    const float* mab2 = (const float*)d_in[24];
    const float* lcW1 = (const float*)d_in[25];
    const float* lcb1 = (const float*)d_in[26];
    const float* lcW2 = (const float*)d_in[27];
    const float* lcb2 = (const float*)d_in[28];
    const float* mcW1 = (const float*)d_in[29];
    const float* mcb1 = (const float*)d_in[30];
    const float* mcW2 = (const float*)d_in[31];
    const float* mcb2 = (const float*)d_in[32];

    float* out = (float*)d_out;
    char* ws = (char*)d_ws;
    size_t off = 0;
    auto alloc = [&](size_t bytes) -> void* {
        void* p = ws + off;
        off += (bytes + 255) & ~(size_t)255;
        return p;
    };
    float* U    = (float*)alloc((size_t)NN * 128 * 4);  // 128 MB ping-pong
    int* counts = (int*)alloc((size_t)NN * 4);
    int* offs   = (int*)alloc((size_t)(NN + 1) * 4);
    int* cursor = (int*)alloc((size_t)NN * 4);
    int* ssrc   = (int*)alloc((size_t)EE * 4);
    float4* sea = (float4*)alloc((size_t)EE * 16);
    int* bsum   = (int*)alloc(512 * 4);
    int* bbase  = (int*)alloc(512 * 4);
    int* bscr   = (int*)alloc(512 * 4);
    float* Lg   = (float*)alloc((size_t)NN * 4);
    float* pooled = (float*)alloc((size_t)BB * 128 * 4);
    int* locInt = (int*)alloc((size_t)BB * 4);

    const int* src = ei;
    const int* dstA = ei + EE;
    float* V = out + 4096;
    float* agg0 = U;

    // weight packs live in `cursor` (1 MB; dead after csr_fill, pack needs 192 KB)
    uint4* wpack = (uint4*)cursor;

    hipMemsetAsync(counts, 0, (size_t)NN * 4, stream);
    csr_count<<<EE / 256, 256, 0, stream>>>(dstA, counts, EE);
    scan512<<<NN / 512, 512, 0, stream>>>(counts, offs, bsum);
    scan512<<<1, 512, 0, stream>>>(bsum, bbase, bscr);
    scan_fix<<<NN / 512, 512, 0, stream>>>(offs, bbase, cursor, NN, EE);
    csr_fill<<<EE / 256, 256, 0, stream>>>(dstA, src, (const float4*)ea, cursor, ssrc, sea, EE);
    pack3<<<3, 256, 0, stream>>>(W1, W2, laW1, wpack);   // after csr_fill: cursor is dead

    agg_l0<<<NN / 256, 256, 0, stream>>>(x, ssrc, sea, offs, We0, be0, agg0);
    update_l0<<<NN / 128, 256, 0, stream>>>(x, agg0, W0, b0, V);
    // U = h1 + sum(msg)  (self folded in)
    agg_l<<<NN / 32, 256, 0, stream>>>((const float2*)V, ssrc, sea, offs, We1, be1, (float2*)U);
    gemm_mfma<<<NN / 256, 256, 0, stream>>>(U, wpack, wpack + 2048, b1, U);          // h2 in U
    agg_l<<<NN / 32, 256, 0, stream>>>((const float2*)U, ssrc, sea, offs, We2, be2, (float2*)V);
    gemm_mfma<<<NN / 256, 256, 0, stream>>>(V, wpack + 4096, wpack + 6144, b2, V);   // emb in V

    gemm_logit_mfma<<<NN / 256, 256, 0, stream>>>(V, wpack + 8192, wpack + 10240, lab1, laW2, lab2, Lg);
    sample_k<<<BB, 256, 0, stream>>>(Lg, out, locInt);

    pool_k<<<BB, 512, 0, stream>>>(V, pooled);
    heads_k<<<BB, 128, 0, stream>>>(V, pooled, locInt, maW1, mab1, maW2, mab2,
                                    lcW1, lcb1, lcW2, lcb2, mcW1, mcb1, mcW2, mcb2, out);
}

// Round 8
// 854.879 us; speedup vs baseline: 1.1029x; 1.1029x over previous
//
#include <hip/hip_runtime.h>
#include <cstdint>
#include <cstddef>

#define NN 262144
#define EE 1048576
#define BB 512
#define SEG 512

// ---------------- Threefry-2x32 (exact JAX replica) ----------------
__device__ __forceinline__ unsigned rotl32(unsigned x, int r) {
    return (x << r) | (x >> (32 - r));
}

__device__ __forceinline__ void tf2x32(unsigned k0, unsigned k1, unsigned x0, unsigned x1,
                                       unsigned& o0, unsigned& o1) {
    unsigned ks[3] = {k0, k1, k0 ^ k1 ^ 0x1BD11BDAu};
    x0 += ks[0]; x1 += ks[1];
    const int R0[4] = {13, 15, 26, 6};
    const int R1[4] = {17, 29, 16, 24};
#pragma unroll
    for (int i = 0; i < 5; ++i) {
        const int* R = (i & 1) ? R1 : R0;
#pragma unroll
        for (int j = 0; j < 4; ++j) {
            x0 += x1;
            x1 = rotl32(x1, R[j]);
            x1 ^= x0;
        }
        x0 += ks[(i + 1) % 3];
        x1 += ks[(i + 2) % 3] + (unsigned)(i + 1);
    }
    o0 = x0; o1 = x1;
}

__device__ __forceinline__ float unif_loc(unsigned idx) {
    unsigned j = idx & (NN / 2 - 1);
    unsigned half = idx >> 17;
    unsigned o0, o1;
    tf2x32(0u, 42u, j, j + (unsigned)(NN / 2), o0, o1);
    unsigned bits = half ? o1 : o0;
    float f = __uint_as_float((bits >> 9) | 0x3F800000u) - 1.0f;
    const float minv = 1e-6f;
    const float maxv = 1.0f - 1e-6f;
    const float span = maxv - minv;
    return fmaxf(minv, __fadd_rn(__fmul_rn(f, span), minv));
}

// ---------------- CSR build ----------------
__global__ void csr_count(const int* __restrict__ dst, int* __restrict__ counts, int E) {
    int i = blockIdx.x * 256 + threadIdx.x;
    if (i < E) atomicAdd(&counts[dst[i]], 1);
}

__global__ void scan512(const int* __restrict__ in, int* __restrict__ outExcl, int* __restrict__ bsum) {
    __shared__ int s[512];
    int b = blockIdx.x, tid = threadIdx.x;
    int v = in[(size_t)b * 512 + tid];
    s[tid] = v;
    __syncthreads();
    for (int d = 1; d < 512; d <<= 1) {
        int add = (tid >= d) ? s[tid - d] : 0;
        __syncthreads();
        s[tid] += add;
        __syncthreads();
    }
    outExcl[(size_t)b * 512 + tid] = s[tid] - v;
    if (tid == 511) bsum[b] = s[511];
}

__global__ void scan_fix(int* __restrict__ offs, const int* __restrict__ bbase,
                         int* __restrict__ cursor, int N, int E) {
    int gid = blockIdx.x * 512 + threadIdx.x;
    int v = offs[gid] + bbase[blockIdx.x];
    offs[gid] = v;
    cursor[gid] = v;
    if (gid == 0) offs[N] = E;
}

__global__ void csr_fill(const int* __restrict__ dst, const int* __restrict__ src,
                         const float4* __restrict__ ea, int* __restrict__ cursor,
                         int* __restrict__ ssrc, float4* __restrict__ sea, int E) {
    int i = blockIdx.x * 256 + threadIdx.x;
    if (i < E) {
        int p = atomicAdd(&cursor[dst[i]], 1);
        ssrc[p] = src[i];
        sea[p] = ea[i];
    }
}

// ---------------- Layer 0: aggregate (dim 8) ----------------
__global__ void agg_l0(const float* __restrict__ x, const int* __restrict__ ssrc,
                       const float4* __restrict__ sea, const int* __restrict__ offs,
                       const float* __restrict__ We0, const float* __restrict__ be0,
                       float* __restrict__ out) {
    __shared__ float Ws[32];
    __shared__ float bs[8];
    int tid = threadIdx.x;
    if (tid < 32) Ws[tid] = We0[tid];
    if (tid < 8) bs[tid] = be0[tid];
    __syncthreads();
    int n = blockIdx.x * 256 + tid;
    float a[8] = {0.f, 0.f, 0.f, 0.f, 0.f, 0.f, 0.f, 0.f};
    int pb = offs[n], pe = offs[n + 1];
    for (int p = pb; p < pe; ++p) {
        int s = ssrc[p];
        float4 ev = sea[p];
        float4 xa = *(const float4*)(x + (size_t)s * 8);
        float4 xb = *(const float4*)(x + (size_t)s * 8 + 4);
        float xs[8] = {xa.x, xa.y, xa.z, xa.w, xb.x, xb.y, xb.z, xb.w};
#pragma unroll
        for (int j2 = 0; j2 < 8; ++j2) {
            float m = xs[j2] + bs[j2] + ev.x * Ws[j2] + ev.y * Ws[8 + j2] +
                      ev.z * Ws[16 + j2] + ev.w * Ws[24 + j2];
            a[j2] += fmaxf(m, 0.f);
        }
    }
    float4 o0 = {a[0], a[1], a[2], a[3]};
    float4 o1 = {a[4], a[5], a[6], a[7]};
    *(float4*)(out + (size_t)n * 8) = o0;
    *(float4*)(out + (size_t)n * 8 + 4) = o1;
}

// ---------------- Layer 0 update ----------------
__global__ __launch_bounds__(256) void update_l0(const float* __restrict__ x,
                                                 const float* __restrict__ agg0,
                                                 const float* __restrict__ W0,
                                                 const float* __restrict__ b0,
                                                 float* __restrict__ h1) {
    __shared__ float Ws[8 * 128];
    __shared__ float bs[128];
    int tid = threadIdx.x;
#pragma unroll
    for (int i = tid; i < 1024; i += 256) Ws[i] = W0[i];
    if (tid < 128) bs[tid] = b0[tid];
    __syncthreads();
    int sub = tid >> 7;
    int c = tid & 127;
    float bias = bs[c];
    float wcol[8];
#pragma unroll
    for (int k = 0; k < 8; ++k) wcol[k] = Ws[k * 128 + c];
    int base = blockIdx.x * 128;
    for (int it = 0; it < 64; ++it) {
        int node = base + it * 2 + sub;
        const float* xp = x + (size_t)node * 8;
        const float* ap = agg0 + (size_t)node * 8;
        float4 xa = *(const float4*)xp;
        float4 xb = *(const float4*)(xp + 4);
        float4 aa = *(const float4*)ap;
        float4 ab = *(const float4*)(ap + 4);
        float t[8] = {xa.x + aa.x, xa.y + aa.y, xa.z + aa.z, xa.w + aa.w,
                      xb.x + ab.x, xb.y + ab.y, xb.z + ab.z, xb.w + ab.w};
        float acc = bias;
#pragma unroll
        for (int k = 0; k < 8; ++k) acc = fmaf(t[k], wcol[k], acc);
        h1[(size_t)node * 128 + c] = fmaxf(acc, 0.f);
    }
}

// ---------------- Layers 1,2: fused msg+aggregate (round-5 version) ----------------
__global__ __launch_bounds__(256) void agg_l(const float2* __restrict__ h2,
                                             const int* __restrict__ ssrc,
                                             const float4* __restrict__ sea,
                                             const int* __restrict__ offs,
                                             const float* __restrict__ We,
                                             const float* __restrict__ be,
                                             float2* __restrict__ out) {
    int tid = threadIdx.x;
    int lane = tid & 63;
    int n0 = blockIdx.x * 32 + (tid >> 6) * 8;
    n0 = __builtin_amdgcn_readfirstlane(n0);
    const float2* We2 = (const float2*)We;
    float2 w0 = We2[lane], w1 = We2[64 + lane], w2 = We2[128 + lane], w3 = We2[192 + lane];
    float2 bv = ((const float2*)be)[lane];

    int b0  = __builtin_amdgcn_readfirstlane(offs[n0 + 0]);
    int nb0 = __builtin_amdgcn_readfirstlane(offs[n0 + 1]);
    int nb1 = __builtin_amdgcn_readfirstlane(offs[n0 + 2]);
    int nb2 = __builtin_amdgcn_readfirstlane(offs[n0 + 3]);
    int nb3 = __builtin_amdgcn_readfirstlane(offs[n0 + 4]);
    int nb4 = __builtin_amdgcn_readfirstlane(offs[n0 + 5]);
    int nb5 = __builtin_amdgcn_readfirstlane(offs[n0 + 6]);
    int nb6 = __builtin_amdgcn_readfirstlane(offs[n0 + 7]);
    int nb7 = __builtin_amdgcn_readfirstlane(offs[n0 + 8]);
    int pend = nb7;

    float2 acc = {0.f, 0.f};
    float2* optr = out + (size_t)n0 * 64 + lane;

#define FLUSH(pp)                                        \
    while ((pp) == nb0) {                                \
        *optr = acc;                                     \
        acc.x = 0.f; acc.y = 0.f;                        \
        optr += 64;                                      \
        nb0 = nb1; nb1 = nb2; nb2 = nb3; nb3 = nb4;      \
        nb4 = nb5; nb5 = nb6; nb6 = nb7; nb7 = 0x7FFFFFFF; \
    }

#define ACC(hv, ev)                                                                     \
    {                                                                                   \
        float mx = hv.x + bv.x + ev.x * w0.x + ev.y * w1.x + ev.z * w2.x + ev.w * w3.x; \
        float my = hv.y + bv.y + ev.x * w0.y + ev.y * w1.y + ev.z * w2.y + ev.w * w3.y; \
        acc.x += fmaxf(mx, 0.f);                                                        \
        acc.y += fmaxf(my, 0.f);                                                        \
    }

    int p = b0;
    for (; p + 8 <= pend; p += 8) {
        int s_[8];
#pragma unroll
        for (int j = 0; j < 8; ++j) s_[j] = ssrc[p + j];
        float4 e_[8];
#pragma unroll
        for (int j = 0; j < 8; ++j) e_[j] = sea[p + j];
        float2 h_[8];
#pragma unroll
        for (int j = 0; j < 8; ++j) h_[j] = h2[(size_t)s_[j] * 64 + lane];
#pragma unroll
        for (int j = 0; j < 8; ++j) {
            FLUSH(p + j)
            ACC(h_[j], e_[j])
        }
    }
    for (; p < pend; ++p) {
        FLUSH(p)
        int s0 = ssrc[p];
        float4 e0 = sea[p];
        float2 ha = h2[(size_t)s0 * 64 + lane];
        ACC(ha, e0)
    }
    FLUSH(pend)
#undef ACC
#undef FLUSH
}

// ====== split-bf16 MFMA GEMM (round-5 structure, measured 99.6 µs) ======
typedef __attribute__((ext_vector_type(8))) short bf16x8;
typedef __attribute__((ext_vector_type(4))) float f32x4;

__device__ __forceinline__ ushort bf16r(float x) {   // fp32 -> bf16 RNE bits
    unsigned u = __float_as_uint(x);
    return (ushort)((u + 0x7FFFu + ((u >> 16) & 1u)) >> 16);
}
__device__ __forceinline__ float bf2f(ushort h) {
    return __uint_as_float(((unsigned)h) << 16);
}

// Pack W [128x128 row-major, k-major] into MFMA B-fragments, hi+lo.
__global__ void pack3(const float* __restrict__ W1, const float* __restrict__ W2,
                      const float* __restrict__ LA, uint4* __restrict__ dst) {
    const float* W = (blockIdx.x == 0) ? W1 : (blockIdx.x == 1) ? W2 : LA;
    uint4* ph = dst + (size_t)blockIdx.x * 4096;
    uint4* pl = ph + 2048;
    int t = threadIdx.x;
    int l = t & 63, q = t >> 6;
    int lo = l & 15, kg = l >> 4;
    for (int i = 0; i < 8; ++i) {
        int combo = q * 8 + i;          // 0..31 = (kc, n)
        int kc = combo >> 3, n = combo & 7;
        ushort h8[8], l8[8];
#pragma unroll
        for (int j = 0; j < 8; ++j) {
            float wv = W[(size_t)(kc * 32 + kg * 8 + j) * 128 + n * 16 + lo];
            ushort hh = bf16r(wv);
            h8[j] = hh;
            l8[j] = bf16r(wv - bf2f(hh));
        }
        int idx = (kc * 8 + n) * 64 + l;
        ph[idx] = *(const uint4*)h8;
        pl[idx] = *(const uint4*)l8;
    }
}

__device__ __forceinline__ void conv_frag(const float4& r0, const float4& r1,
                                          bf16x8& ah, bf16x8& al) {
    float av[8] = {r0.x, r0.y, r0.z, r0.w, r1.x, r1.y, r1.z, r1.w};
#pragma unroll
    for (int j = 0; j < 8; ++j) {
        ushort hh = bf16r(av[j]);
        ah[j] = (short)hh;
        al[j] = (short)bf16r(av[j] - bf2f(hh));
    }
}

__device__ __forceinline__ void load_a_frags(const float* P, const float* Q, int r0,
                                             int lo, int kg, int kc,
                                             bf16x8& ah0, bf16x8& al0,
                                             bf16x8& ah1, bf16x8& al1) {
#pragma unroll
    for (int m = 0; m < 2; ++m) {
        const float* ap = P + (size_t)(r0 + m * 16 + lo) * 128 + kc * 32 + kg * 8;
        float4 p0 = *(const float4*)ap;
        float4 p1 = *(const float4*)(ap + 4);
        if (Q) {
            const float* qp = Q + (size_t)(r0 + m * 16 + lo) * 128 + kc * 32 + kg * 8;
            float4 q0 = *(const float4*)qp;
            float4 q1 = *(const float4*)(qp + 4);
            p0.x += q0.x; p0.y += q0.y; p0.z += q0.z; p0.w += q0.w;
            p1.x += q1.x; p1.y += q1.y; p1.z += q1.z; p1.w += q1.w;
        }
        bf16x8 ah, al;
        conv_frag(p0, p1, ah, al);
        if (m == 0) { ah0 = ah; al0 = al; } else { ah1 = ah; al1 = al; }
    }
}

__global__ __launch_bounds__(256) void gemm_mfma(const float* __restrict__ P, const float* Q,
                                                 const uint4* __restrict__ Wh,
                                                 const uint4* __restrict__ Wl,
                                                 const float* __restrict__ bias,
                                                 float* out) {
    int tid = threadIdx.x;
    int w = tid >> 6, l = tid & 63;
    int r0 = blockIdx.x * 128 + w * 32;
    int lo = l & 15, kg = l >> 4;
    const bf16x8* Bh = (const bf16x8*)Wh;
    const bf16x8* Bl = (const bf16x8*)Wl;
    f32x4 acc[2][8];
#pragma unroll
    for (int m = 0; m < 2; ++m)
#pragma unroll
        for (int n = 0; n < 8; ++n) acc[m][n] = (f32x4){0.f, 0.f, 0.f, 0.f};

    for (int kc = 0; kc < 4; ++kc) {
        bf16x8 ah0, al0, ah1, al1;
        load_a_frags(P, Q, r0, lo, kg, kc, ah0, al0, ah1, al1);
#pragma unroll
        for (int h2i = 0; h2i < 2; ++h2i) {
            bf16x8 bh[4], bl[4];
#pragma unroll
            for (int nn = 0; nn < 4; ++nn) {
                int idx = (kc * 8 + h2i * 4 + nn) * 64 + l;
                bh[nn] = Bh[idx];
                bl[nn] = Bl[idx];
            }
#pragma unroll
            for (int nn = 0; nn < 4; ++nn) {
                int n = h2i * 4 + nn;
                acc[0][n] = __builtin_amdgcn_mfma_f32_16x16x32_bf16(ah0, bh[nn], acc[0][n], 0, 0, 0);
                acc[0][n] = __builtin_amdgcn_mfma_f32_16x16x32_bf16(al0, bh[nn], acc[0][n], 0, 0, 0);
                acc[0][n] = __builtin_amdgcn_mfma_f32_16x16x32_bf16(ah0, bl[nn], acc[0][n], 0, 0, 0);
                acc[1][n] = __builtin_amdgcn_mfma_f32_16x16x32_bf16(ah1, bh[nn], acc[1][n], 0, 0, 0);
                acc[1][n] = __builtin_amdgcn_mfma_f32_16x16x32_bf16(al1, bh[nn], acc[1][n], 0, 0, 0);
                acc[1][n] = __builtin_amdgcn_mfma_f32_16x16x32_bf16(ah1, bl[nn], acc[1][n], 0, 0, 0);
            }
        }
    }
    float bv[8];
#pragma unroll
    for (int n = 0; n < 8; ++n) bv[n] = bias[n * 16 + lo];
#pragma unroll
    for (int m = 0; m < 2; ++m)
#pragma unroll
        for (int n = 0; n < 8; ++n)
#pragma unroll
            for (int v = 0; v < 4; ++v) {
                size_t g = (size_t)(r0 + m * 16 + kg * 4 + v) * 128 + n * 16 + lo;
                out[g] = fmaxf(acc[m][n][v] + bv[n], 0.f);
            }
}

// ====== layer-2 GEMM with fused logit head + pooled segment-sum ======
// emb = relu((P+Q)@W2+b2)  -> out (V)
// Lg  = relu(emb@laW1+lab1)@laW2+lab2  (via LDS tile restage, bitwise-
//       identical numerics to the former standalone gemm_logit_mfma)
// pooled[g] += colsum(emb tile)  (one atomicAdd per col per block)
__global__ __launch_bounds__(256) void gemm_emb_fused(const float* __restrict__ P, const float* Q,
                                                      const uint4* __restrict__ Wh,
                                                      const uint4* __restrict__ Wl,
                                                      const float* __restrict__ bias,
                                                      const uint4* __restrict__ LWh,
                                                      const uint4* __restrict__ LWl,
                                                      const float* __restrict__ lb1,
                                                      const float* __restrict__ lw2,
                                                      const float* __restrict__ lb2,
                                                      float* out,
                                                      float* __restrict__ pooled,
                                                      float* __restrict__ Lg) {
    __shared__ float eL[4][32][132];   // per-wave emb tile, padded (2-way max)
    __shared__ float poolL[4][128];
    int tid = threadIdx.x;
    int w = tid >> 6, l = tid & 63;
    int r0 = blockIdx.x * 128 + w * 32;
    int lo = l & 15, kg = l >> 4;
    const bf16x8* Bh = (const bf16x8*)Wh;
    const bf16x8* Bl = (const bf16x8*)Wl;
    f32x4 acc[2][8];
#pragma unroll
    for (int m = 0; m < 2; ++m)
#pragma unroll
        for (int n = 0; n < 8; ++n) acc[m][n] = (f32x4){0.f, 0.f, 0.f, 0.f};

    for (int kc = 0; kc < 4; ++kc) {
        bf16x8 ah0, al0, ah1, al1;
        load_a_frags(P, Q, r0, lo, kg, kc, ah0, al0, ah1, al1);
#pragma unroll
        for (int h2i = 0; h2i < 2; ++h2i) {
            bf16x8 bh[4], bl[4];
#pragma unroll
            for (int nn = 0; nn < 4; ++nn) {
                int idx = (kc * 8 + h2i * 4 + nn) * 64 + l;
                bh[nn] = Bh[idx];
                bl[nn] = Bl[idx];
            }
#pragma unroll
            for (int nn = 0; nn < 4; ++nn) {
                int n = h2i * 4 + nn;
                acc[0][n] = __builtin_amdgcn_mfma_f32_16x16x32_bf16(ah0, bh[nn], acc[0][n], 0, 0, 0);
                acc[0][n] = __builtin_amdgcn_mfma_f32_16x16x32_bf16(al0, bh[nn], acc[0][n], 0, 0, 0);
                acc[0][n] = __builtin_amdgcn_mfma_f32_16x16x32_bf16(ah0, bl[nn], acc[0][n], 0, 0, 0);
                acc[1][n] = __builtin_amdgcn_mfma_f32_16x16x32_bf16(ah1, bh[nn], acc[1][n], 0, 0, 0);
                acc[1][n] = __builtin_amdgcn_mfma_f32_16x16x32_bf16(al1, bh[nn], acc[1][n], 0, 0, 0);
                acc[1][n] = __builtin_amdgcn_mfma_f32_16x16x32_bf16(ah1, bl[nn], acc[1][n], 0, 0, 0);
            }
        }
    }
    // ---- epilogue: emb = relu(acc+b), store + stage + col-partial-sum ----
    float bv[8];
#pragma unroll
    for (int n = 0; n < 8; ++n) bv[n] = bias[n * 16 + lo];
    float psum[8];
#pragma unroll
    for (int n = 0; n < 8; ++n) psum[n] = 0.f;
#pragma unroll
    for (int m = 0; m < 2; ++m)
#pragma unroll
        for (int n = 0; n < 8; ++n)
#pragma unroll
            for (int v = 0; v < 4; ++v) {
                float e = fmaxf(acc[m][n][v] + bv[n], 0.f);
                size_t g = (size_t)(r0 + m * 16 + kg * 4 + v) * 128 + n * 16 + lo;
                out[g] = e;
                eL[w][m * 16 + kg * 4 + v][n * 16 + lo] = e;
                psum[n] += e;
            }
    // ---- pooled: collapse kg groups, cross-wave reduce, 1 atomic/col ----
#pragma unroll
    for (int n = 0; n < 8; ++n) {
        psum[n] += __shfl_xor(psum[n], 16);
        psum[n] += __shfl_xor(psum[n], 32);
    }
    if (l < 16) {
#pragma unroll
        for (int n = 0; n < 8; ++n) poolL[w][n * 16 + l] = psum[n];
    }
    __syncthreads();
    if (tid < 128) {
        float s = poolL[0][tid] + poolL[1][tid] + poolL[2][tid] + poolL[3][tid];
        atomicAdd(&pooled[(blockIdx.x >> 2) * 128 + tid], s);
    }
    // ---- logit head: restage emb tile as A-frags from LDS ----
    const bf16x8* LBh = (const bf16x8*)LWh;
    const bf16x8* LBl = (const bf16x8*)LWl;
    f32x4 acc2[2][8];
#pragma unroll
    for (int m = 0; m < 2; ++m)
#pragma unroll
        for (int n = 0; n < 8; ++n) acc2[m][n] = (f32x4){0.f, 0.f, 0.f, 0.f};
    for (int kc = 0; kc < 4; ++kc) {
        bf16x8 ah[2], al[2];
#pragma unroll
        for (int m = 0; m < 2; ++m) {
            const float* ep = &eL[w][m * 16 + lo][kc * 32 + kg * 8];
            float4 a0 = *(const float4*)ep;
            float4 a1 = *(const float4*)(ep + 4);
            conv_frag(a0, a1, ah[m], al[m]);
        }
#pragma unroll
        for (int h2i = 0; h2i < 2; ++h2i) {
            bf16x8 bh[4], bl[4];
#pragma unroll
            for (int nn = 0; nn < 4; ++nn) {
                int idx = (kc * 8 + h2i * 4 + nn) * 64 + l;
                bh[nn] = LBh[idx];
                bl[nn] = LBl[idx];
            }
#pragma unroll
            for (int nn = 0; nn < 4; ++nn) {
                int n = h2i * 4 + nn;
                acc2[0][n] = __builtin_amdgcn_mfma_f32_16x16x32_bf16(ah[0], bh[nn], acc2[0][n], 0, 0, 0);
                acc2[0][n] = __builtin_amdgcn_mfma_f32_16x16x32_bf16(al[0], bh[nn], acc2[0][n], 0, 0, 0);
                acc2[0][n] = __builtin_amdgcn_mfma_f32_16x16x32_bf16(ah[0], bl[nn], acc2[0][n], 0, 0, 0);
                acc2[1][n] = __builtin_amdgcn_mfma_f32_16x16x32_bf16(ah[1], bh[nn], acc2[1][n], 0, 0, 0);
                acc2[1][n] = __builtin_amdgcn_mfma_f32_16x16x32_bf16(al[1], bh[nn], acc2[1][n], 0, 0, 0);
                acc2[1][n] = __builtin_amdgcn_mfma_f32_16x16x32_bf16(ah[1], bl[nn], acc2[1][n], 0, 0, 0);
            }
        }
    }
    float b1v[8], w2v[8];
#pragma unroll
    for (int n = 0; n < 8; ++n) {
        b1v[n] = lb1[n * 16 + lo];
        w2v[n] = lw2[n * 16 + lo];
    }
    float lb2v = lb2[0];
#pragma unroll
    for (int m = 0; m < 2; ++m)
#pragma unroll
        for (int v = 0; v < 4; ++v) {
            float s = 0.f;
#pragma unroll
            for (int n = 0; n < 8; ++n)
                s += fmaxf(acc2[m][n][v] + b1v[n], 0.f) * w2v[n];
            s += __shfl_xor(s, 8);
            s += __shfl_xor(s, 4);
            s += __shfl_xor(s, 2);
            s += __shfl_xor(s, 1);
            if (lo == 0) Lg[r0 + m * 16 + kg * 4 + v] = s + lb2v;
        }
}

// ---------------- per-graph softmax + Gumbel-max sampling ----------------
__global__ void sample_k(const float* __restrict__ L, float* __restrict__ ob,
                         int* __restrict__ locInt) {
    int g = blockIdx.x, tid = threadIdx.x;
    __shared__ float sh[512];
    __shared__ float rb[256];
    __shared__ int ib[256];
    float l0 = L[g * 512 + tid];
    float l1 = L[g * 512 + 256 + tid];
    rb[tid] = fmaxf(l0, l1);
    __syncthreads();
    for (int s2 = 128; s2 > 0; s2 >>= 1) {
        if (tid < s2) rb[tid] = fmaxf(rb[tid], rb[tid + s2]);
        __syncthreads();
    }
    float mx = rb[0];
    __syncthreads();
    float s0 = l0 - mx, s1 = l1 - mx;
    sh[tid] = s0; sh[256 + tid] = s1;
    float e0 = expf(s0), e1 = expf(s1);
    rb[tid] = e0 + e1;
    __syncthreads();
    for (int s2 = 128; s2 > 0; s2 >>= 1) {
        if (tid < s2) rb[tid] += rb[tid + s2];
        __syncthreads();
    }
    float denom = rb[0];
    __syncthreads();
    rb[tid] = e0 * s0 + e1 * s1;
    __syncthreads();
    for (int s2 = 128; s2 > 0; s2 >>= 1) {
        if (tid < s2) rb[tid] += rb[tid + s2];
        __syncthreads();
    }
    float sum2 = rb[0];
    __syncthreads();
    unsigned i0 = (unsigned)(g * 512 + tid);
    unsigned i1 = i0 + 256u;
    float p0 = l0 - logf(-logf(unif_loc(i0)));
    float p1 = l1 - logf(-logf(unif_loc(i1)));
    rb[tid] = fmaxf(p0, p1);
    __syncthreads();
    for (int s2 = 128; s2 > 0; s2 >>= 1) {
        if (tid < s2) rb[tid] = fmaxf(rb[tid], rb[tid + s2]);
        __syncthreads();
    }
    float pmax = rb[0];
    __syncthreads();
    int c0 = (p0 >= pmax) ? tid : 0x7FFFFFFF;
    int c1 = (p1 >= pmax) ? (tid + 256) : 0x7FFFFFFF;
    ib[tid] = min(c0, c1);
    __syncthreads();
    for (int s2 = 128; s2 > 0; s2 >>= 1) {
        if (tid < s2) ib[tid] = min(ib[tid], ib[tid + s2]);
        __syncthreads();
    }
    if (tid == 0) {
        int li = ib[0];
        float logD = logf(denom);
        ob[g] = (float)(g * 512 + li);
        ob[1024 + g] = sh[li] - logD;
        ob[2048 + g] = logD - sum2 / denom;
        locInt[g] = g * 512 + li;
    }
}

// ---------------- heads ----------------
__global__ void heads_k(const float* __restrict__ emb, const float* __restrict__ pooled,
                        const int* __restrict__ locInt,
                        const float* __restrict__ maW1, const float* __restrict__ mab1,
                        const float* __restrict__ maW2, const float* __restrict__ mab2,
                        const float* __restrict__ lcW1, const float* __restrict__ lcb1,
                        const float* __restrict__ lcW2, const float* __restrict__ lcb2,
                        const float* __restrict__ mcW1, const float* __restrict__ mcb1,
                        const float* __restrict__ mcW2, const float* __restrict__ mcb2,
                        float* __restrict__ ob) {
    int g = blockIdx.x, tid = threadIdx.x;
    __shared__ float sel[128], pl[128];
    __shared__ float red[4][128];
    __shared__ float red1[128];
    __shared__ float mcv_sh;
    sel[tid] = emb[(size_t)locInt[g] * 128 + tid];
    pl[tid] = pooled[g * 128 + tid];
    __syncthreads();
    float h = mab1[tid];
    for (int k = 0; k < 128; ++k) h = fmaf(sel[k], maW1[k * 128 + tid], h);
    h = fmaxf(h, 0.f);
    red[0][tid] = h * maW2[tid * 4 + 0];
    red[1][tid] = h * maW2[tid * 4 + 1];
    red[2][tid] = h * maW2[tid * 4 + 2];
    red[3][tid] = h * maW2[tid * 4 + 3];
    __syncthreads();
    for (int s2 = 64; s2 > 0; s2 >>= 1) {
        if (tid < s2) {
            red[0][tid] += red[0][tid + s2];
            red[1][tid] += red[1][tid + s2];
            red[2][tid] += red[2][tid + s2];
            red[3][tid] += red[3][tid + s2];
        }
        __syncthreads();
    }
    float h2 = mcb1[tid];
    for (int k = 0; k < 128; ++k) h2 = fmaf(sel[k], mcW1[k * 128 + tid], h2);
    h2 = fmaxf(h2, 0.f);
    red1[tid] = h2 * mcW2[tid];
    __syncthreads();
    for (int s2 = 64; s2 > 0; s2 >>= 1) {
        if (tid < s2) red1[tid] += red1[tid + s2];
        __syncthreads();
    }
    if (tid == 0) mcv_sh = red1[0] + mcb2[0];
    __syncthreads();
    float h3 = lcb1[tid];
    for (int k = 0; k < 128; ++k) h3 = fmaf(pl[k], lcW1[k * 128 + tid], h3);
    h3 = fmaxf(h3, 0.f);
    red1[tid] = h3 * lcW2[tid];
    __syncthreads();
    for (int s2 = 64; s2 > 0; s2 >>= 1) {
        if (tid < s2) red1[tid] += red1[tid + s2];
        __syncthreads();
    }
    if (tid == 0) {
        float lcv = red1[0] + lcb2[0];
        float lg[4];
#pragma unroll
        for (int c = 0; c < 4; ++c) lg[c] = red[c][0] + mab2[c];
        unsigned fk0, fk1;
        tf2x32(0u, 42u, 0u, 1u, fk0, fk1);
        float gmb[4];
#pragma unroll
        for (int c = 0; c < 4; ++c) {
            unsigned m = (unsigned)(g * 4 + c);
            unsigned j = m & 1023u;
            unsigned halfb = m >> 10;
            unsigned o0, o1;
            tf2x32(fk0, fk1, j, j + 1024u, o0, o1);
            unsigned bits = halfb ? o1 : o0;
            float f = __uint_as_float((bits >> 9) | 0x3F800000u) - 1.0f;
            const float tiny = 1.17549435e-38f;
            float u = fmaxf(tiny, __fadd_rn(__fmul_rn(f, 1.0f), tiny));
            gmb[c] = -logf(-logf(u));
        }
        int best = 0;
        float bz = gmb[0] + lg[0];
#pragma unroll
        for (int c = 1; c < 4; ++c) {
            float z = gmb[c] + lg[c];
            if (z > bz) { bz = z; best = c; }
        }
        float M = fmaxf(fmaxf(lg[0], lg[1]), fmaxf(lg[2], lg[3]));
        float se = 0.f;
#pragma unroll
        for (int c = 0; c < 4; ++c) se += expf(lg[c] - M);
        float lse = M + logf(se);
        float ent = 0.f;
#pragma unroll
        for (int c = 0; c < 4; ++c) {
            float lp = lg[c] - lse;
            ent -= expf(lp) * lp;
        }
        ob[512 + g] = (float)best;
        ob[1536 + g] = lg[best] - lse;
        ob[2560 + g] = ent;
        ob[3072 + g] = lcv;
        ob[3584 + g] = mcv_sh;
    }
}

// ---------------- launch ----------------
extern "C" void kernel_launch(void* const* d_in, const int* in_sizes, int n_in,
                              void* d_out, int out_size, void* d_ws, size_t ws_size,
                              hipStream_t stream) {
    const float* x   = (const float*)d_in[0];
    const int* ei    = (const int*)d_in[1];
    const float* ea  = (const float*)d_in[2];
    const float* We0 = (const float*)d_in[5];
    const float* be0 = (const float*)d_in[6];
    const float* W0  = (const float*)d_in[7];
    const float* b0  = (const float*)d_in[8];
    const float* We1 = (const float*)d_in[9];
    const float* be1 = (const float*)d_in[10];
    const float* W1  = (const float*)d_in[11];
    const float* b1  = (const float*)d_in[12];
    const float* We2 = (const float*)d_in[13];
    const float* be2 = (const float*)d_in[14];
    const float* W2  = (const float*)d_in[15];
    const float* b2  = (const float*)d_in[16];
    const float* laW1 = (const float*)d_in[17];
    const float* lab1 = (const float*)d_in[18];
    const float* laW2 = (const float*)d_in[19];
    const float* lab2 = (const float*)d_in[20];
    const float* maW1 = (const float*)d_in[21];
    const float* mab1 = (const float*)d_in[22];
    const float* maW2 = (const float*)d_in[23];
    const float* mab2 = (const float*)d_in[24];
    const float* lcW1 = (const float*)d_in[25];
    const float* lcb1 = (const float*)d_in[26];
    const float* lcW2 = (const float*)d_in[27];
    const float* lcb2 = (const float*)d_in[28];
    const float* mcW1 = (const float*)d_in[29];
    const float* mcb1 = (const float*)d_in[30];
    const float* mcW2 = (const float*)d_in[31];
    const float* mcb2 = (const float*)d_in[32];

    float* out = (float*)d_out;
    char* ws = (char*)d_ws;
    size_t off = 0;
    auto alloc = [&](size_t bytes) -> void* {
        void* p = ws + off;
        off += (bytes + 255) & ~(size_t)255;
        return p;
    };
    float* U    = (float*)alloc((size_t)NN * 128 * 4);  // 128 MB ping-pong
    int* counts = (int*)alloc((size_t)NN * 4);
    int* offs   = (int*)alloc((size_t)(NN + 1) * 4);
    int* cursor = (int*)alloc((size_t)NN * 4);
    int* ssrc   = (int*)alloc((size_t)EE * 4);
    float4* sea = (float4*)alloc((size_t)EE * 16);
    int* bsum   = (int*)alloc(512 * 4);
    int* bbase  = (int*)alloc(512 * 4);
    int* bscr   = (int*)alloc(512 * 4);
    float* Lg   = (float*)alloc((size_t)NN * 4);
    float* pooled = (float*)alloc((size_t)BB * 128 * 4);
    int* locInt = (int*)alloc((size_t)BB * 4);

    const int* src = ei;
    const int* dstA = ei + EE;
    float* V = out + 4096;
    float* agg0 = U;

    // weight packs live in `cursor` (1 MB; dead after csr_fill, pack needs 192 KB)
    uint4* wpack = (uint4*)cursor;

    hipMemsetAsync(counts, 0, (size_t)NN * 4, stream);
    hipMemsetAsync(pooled, 0, (size_t)BB * 128 * 4, stream);
    csr_count<<<EE / 256, 256, 0, stream>>>(dstA, counts, EE);
    scan512<<<NN / 512, 512, 0, stream>>>(counts, offs, bsum);
    scan512<<<1, 512, 0, stream>>>(bsum, bbase, bscr);
    scan_fix<<<NN / 512, 512, 0, stream>>>(offs, bbase, cursor, NN, EE);
    csr_fill<<<EE / 256, 256, 0, stream>>>(dstA, src, (const float4*)ea, cursor, ssrc, sea, EE);
    pack3<<<3, 256, 0, stream>>>(W1, W2, laW1, wpack);   // after csr_fill: cursor is dead

    agg_l0<<<NN / 256, 256, 0, stream>>>(x, ssrc, sea, offs, We0, be0, agg0);
    update_l0<<<NN / 128, 256, 0, stream>>>(x, agg0, W0, b0, V);
    agg_l<<<NN / 32, 256, 0, stream>>>((const float2*)V, ssrc, sea, offs, We1, be1, (float2*)U);
    gemm_mfma<<<NN / 128, 256, 0, stream>>>(V, U, wpack, wpack + 2048, b1, U);
    agg_l<<<NN / 32, 256, 0, stream>>>((const float2*)U, ssrc, sea, offs, We2, be2, (float2*)V);
    // layer-2 GEMM + logit head + pooled, all in one pass
    gemm_emb_fused<<<NN / 128, 256, 0, stream>>>(U, V, wpack + 4096, wpack + 6144, b2,
                                                 wpack + 8192, wpack + 10240, lab1, laW2, lab2,
                                                 V, pooled, Lg);

    sample_k<<<BB, 256, 0, stream>>>(Lg, out, locInt);
    heads_k<<<BB, 128, 0, stream>>>(V, pooled, locInt, maW1, mab1, maW2, mab2,
                                    lcW1, lcb1, lcW2, lcb2, mcW1, mcb1, mcW2, mcb2, out);
}